// Round 1
// 783.074 us; speedup vs baseline: 1.0276x; 1.0276x over previous
//
#include <hip/hip_runtime.h>
#include <math.h>

typedef unsigned int u32;
typedef unsigned long long u64;

#define NANCH 6402
#define NCLS 80
#define TOPK 200
#define MAXN 100

// ---------- helpers ----------
__device__ __forceinline__ u32 sortable_u32(float f) {
  u32 u = __float_as_uint(f);
  return u ^ ((u32)(((int)u) >> 31) | 0x80000000u);
}
__device__ __forceinline__ float unsortable_f(u32 u) {
  u32 f = (u & 0x80000000u) ? (u ^ 0x80000000u) : ~u;
  return __uint_as_float(f);
}

// descending bitonic sort of P (power of 2) u64 keys in LDS, 256 threads
__device__ void bitonic_desc(u64* keys, int P, int tid) {
  for (int k = 2; k <= P; k <<= 1) {
    for (int j = k >> 1; j > 0; j >>= 1) {
      for (int i = tid; i < P; i += 256) {
        int l = i ^ j;
        if (l > i) {
          u64 a = keys[i], b = keys[l];
          bool desc = ((i & k) == 0);
          if (desc ? (a < b) : (a > b)) { keys[i] = b; keys[l] = a; }
        }
      }
      __syncthreads();
    }
  }
}

// ---------- kernel 1: softmax threshold precompute + bbox decode ----------
// thr = m + log(0.05 * den)  =>  (score > 0.05) <=> (logit > thr),
// and score = 0.05 * exp(logit - thr) exactly (monotone, same rounding scale).
template<int W, int HW, int BS, int OFF>
__device__ void prep_level(int t, const float* __restrict__ cls,
                           const float* __restrict__ box,
                           float* __restrict__ thr, float4* __restrict__ bbox) {
  if (t >= 64 * 3 * HW) return;
  int b = t / (3 * HW);
  int rem = t - b * 3 * HW;
  int a = rem / HW;
  int hw = rem - a * HW;

  const float* cbase = cls + ((size_t)b * 243 + (size_t)a * 81) * HW + hw;
  float m = cbase[0];
#pragma unroll 4
  for (int c = 1; c < 81; ++c) m = fmaxf(m, cbase[(size_t)c * HW]);
  double den = 0.0;
#pragma unroll 4
  for (int c = 0; c < 81; ++c) den += (double)expf(cbase[(size_t)c * HW] - m);
  // plane-major layout: p = OFF + a*HW + hw  (coalesced re-read in k_nms)
  thr[(size_t)b * NANCH + OFF + a * HW + hw] = m + logf(0.05f * (float)den);

  // bbox decode
  const float* bb = box + ((size_t)b * 12 + (size_t)a * 4) * HW + hw;
  float d0 = bb[0] * 0.1f;
  float d1 = bb[HW] * 0.1f;
  float d2 = bb[2 * HW] * 0.2f;
  float d3 = bb[3 * HW] * 0.2f;
  const float MR = 4.135166556742356f;  // |log(0.016)| cast to f32
  d2 = fminf(fmaxf(d2, -MR), MR);
  d3 = fminf(fmaxf(d3, -MR), MR);

  int x = hw % W, y = hw / W;
  double r = (a == 0) ? 0.5 : ((a == 1) ? 1.0 : 2.0);
  double hr = sqrt(r), wr = 1.0 / hr;
  double wsd = ((double)BS * wr) * 3.0;
  double hsd = ((double)BS * hr) * 3.0;
  double cc = (double)BS * 0.5;
  double sx = (double)(x * BS), sy = (double)(y * BS);
  float ax0 = (float)((cc - 0.5 * wsd) + sx);
  float ay0 = (float)((cc - 0.5 * hsd) + sy);
  float ax1 = (float)((cc + 0.5 * wsd) + sx);
  float ay1 = (float)((cc + 0.5 * hsd) + sy);

  float px = (ax0 + ax1) * 0.5f, py = (ay0 + ay1) * 0.5f;
  float pw = ax1 - ax0, ph = ay1 - ay0;
  float gx = px + pw * d0, gy = py + ph * d1;
  float gw = pw * expf(d2), gh = ph * expf(d3);
  float x0 = fminf(fmaxf(gx - 0.5f * gw, 0.f), 320.f);
  float y0 = fminf(fmaxf(gy - 0.5f * gh, 0.f), 320.f);
  float x1 = fminf(fmaxf(gx + 0.5f * gw, 0.f), 320.f);
  float y1 = fminf(fmaxf(gy + 0.5f * gh, 0.f), 320.f);
  int n = OFF + hw * 3 + a;  // anchor-major index (matches reference flatten)
  bbox[(size_t)b * NANCH + n] = make_float4(x0, y0, x1, y1);
}

__global__ __launch_bounds__(256) void k_prep(
    const float* c0, const float* c1, const float* c2, const float* c3, const float* c4,
    const float* b0, const float* b1, const float* b2, const float* b3, const float* b4,
    float* thr, float4* bbox) {
  int bid = blockIdx.x, tid = threadIdx.x;
  if (bid < 1200)      prep_level<40, 1600, 8, 0>(bid * 256 + tid, c0, b0, thr, bbox);
  else if (bid < 1500) prep_level<20, 400, 16, 4800>((bid - 1200) * 256 + tid, c1, b1, thr, bbox);
  else if (bid < 1575) prep_level<10, 100, 32, 6000>((bid - 1500) * 256 + tid, c2, b2, thr, bbox);
  else if (bid < 1594) prep_level<5, 25, 64, 6300>((bid - 1575) * 256 + tid, c3, b3, thr, bbox);
  else                 prep_level<3, 9, 128, 6375>((bid - 1594) * 256 + tid, c4, b4, thr, bbox);
}

// ---------- kernel 2: per-(batch,class) top-200 + Fast NMS ----------
// compact: cheap compare against precomputed thr; expf only for ~3% passers
template<int HW, int OFF>
__device__ void compact_level(int b, int ccls, const float* __restrict__ cls,
                              const float* __restrict__ thr,
                              u64* keys, int* cnt, int tid) {
  for (int a = 0; a < 3; ++a) {
    const float* src = cls + ((size_t)b * 243 + (size_t)a * 81 + ccls) * HW;
    const float* tp = thr + (size_t)b * NANCH + OFF + a * HW;
    for (int hw = tid; hw < HW; hw += 256) {
      float l = src[hw];
      float t = tp[hw];
      if (l > t) {
        float s = 0.05f * expf(l - t);  // == exp(l-m)/den within ~1e-7 rel
        int pos = atomicAdd(cnt, 1);
        if (pos < 1024) {
          u32 n = (u32)(OFF + hw * 3 + a);
          keys[pos] = ((u64)__float_as_uint(s) << 32) | (u32)(~n);
        }
      }
    }
  }
}

__global__ __launch_bounds__(256) void k_nms(
    const float* c0, const float* c1, const float* c2, const float* c3, const float* c4,
    const float* __restrict__ thr, const float4* __restrict__ bbox,
    float* __restrict__ val, int* __restrict__ anc) {
  __shared__ u64 keys[1024];
  __shared__ float4 boxes[TOPK];
  __shared__ float area[TOPK];
  __shared__ u32 suppw[8];
  __shared__ int cnt;
  int tid = threadIdx.x;
  int bid = blockIdx.x;
  int b = bid / NCLS;
  int ccls = bid - b * NCLS;
  if (tid == 0) cnt = 0;
  if (tid < 8) suppw[tid] = 0u;
  __syncthreads();

  compact_level<1600, 0>(b, ccls, c0, thr, keys, &cnt, tid);
  compact_level<400, 4800>(b, ccls, c1, thr, keys, &cnt, tid);
  compact_level<100, 6000>(b, ccls, c2, thr, keys, &cnt, tid);
  compact_level<25, 6300>(b, ccls, c3, thr, keys, &cnt, tid);
  compact_level<9, 6375>(b, ccls, c4, thr, keys, &cnt, tid);
  __syncthreads();

  int cntc = min(cnt, 1024);
  int P = (cntc <= 256) ? 256 : ((cntc <= 512) ? 512 : 1024);
  for (int i = cntc + tid; i < P; i += 256) keys[i] = 0ULL;
  __syncthreads();
  bitonic_desc(keys, P, tid);

  int K2 = min(cntc, TOPK);
  for (int kk = tid; kk < K2; kk += 256) {
    u32 n = ~(u32)(keys[kk] & 0xFFFFFFFFULL);
    float4 bx = bbox[(size_t)b * NANCH + n];
    boxes[kk] = bx;
    area[kk] = (bx.z - bx.x) * (bx.w - bx.y);
  }
  __syncthreads();

  // balanced pair-parallel Fast-NMS:
  //   supp[j] = OR_{i<j} (iou(i,j) > 0.5)   (no cascade -> order-free)
  // thread t: columns {pn, K2-1-pn}, i-range parity-split by half.
  // per-lane iters ~= (K2-1)/2 for every lane (balanced, wave-uniform).
  {
    int pn = tid & 127;
    int half = tid >> 7;
    for (int rep = 0; rep < 2; ++rep) {
      int j = rep ? (K2 - 1 - pn) : pn;
      if (rep && j == pn) break;     // same column, rep0 already did it
      if (j < 1 || j >= K2) continue;
      float4 bj = boxes[j];
      float aj = area[j];
      bool sup = false;
      for (int i = half; i < j; i += 2) {
        float4 bi = boxes[i];
        float wx = fmaxf(fminf(bi.z, bj.z) - fmaxf(bi.x, bj.x), 0.f);
        float wy = fmaxf(fminf(bi.w, bj.w) - fmaxf(bi.y, bj.y), 0.f);
        float ov = wx * wy;
        float un = fmaxf(area[i] + aj - ov, 1e-6f);
        bool sp;
        if (ov > un * 0.505f) sp = true;                  // certainly iou > 0.5
        else if (ov > un * 0.495f) sp = (ov / un > 0.5f); // exact IEEE division
        else sp = false;
        if (sp) { sup = true; break; }
      }
      if (sup) atomicOr(&suppw[j >> 5], 1u << (j & 31));
    }
  }
  __syncthreads();

  float* valp = val + (size_t)b * (NCLS * TOPK) + (size_t)ccls * TOPK;
  int* ancp = anc + (size_t)b * (NCLS * TOPK) + (size_t)ccls * TOPK;
  if (tid < TOPK) {
    if (tid < K2) {
      bool supp = (suppw[tid >> 5] >> (tid & 31)) & 1u;
      float s = __uint_as_float((u32)(keys[tid] >> 32));
      u32 n = ~(u32)(keys[tid] & 0xFFFFFFFFULL);
      valp[tid] = supp ? -1.0f : s;
      ancp[tid] = (int)n;
    } else {
      valp[tid] = -1.0f;
      ancp[tid] = -1;
    }
  }
}

// ---------- kernel 3: per-batch global top-100 + dets/labels/coeff gather ----------
__global__ __launch_bounds__(256) void k_top(
    const float* __restrict__ val, const int* __restrict__ anc,
    const float4* __restrict__ bbox,
    const float* f0, const float* f1, const float* f2, const float* f3, const float* f4,
    float* __restrict__ out, float* __restrict__ csel) {
  int b = blockIdx.x, tid = threadIdx.x;
  const float* vp = val + (size_t)b * 16000;

  u32 uloc[63];
#pragma unroll
  for (int k = 0; k < 63; ++k) {
    int i = tid + k * 256;
    uloc[k] = (i < 16000) ? sortable_u32(vp[i]) : 0u;
  }

  __shared__ int partial[256];
  u32 lo = 0u, hi = 0xFFFFFFFFu;
  for (int it = 0; it < 32; ++it) {
    u32 mid = lo + ((hi - lo) >> 1);
    int cme = 0;
#pragma unroll
    for (int k = 0; k < 63; ++k) cme += (uloc[k] >= mid) ? 1 : 0;
    partial[tid] = cme;
    __syncthreads();
    for (int s = 128; s > 0; s >>= 1) {
      if (tid < s) partial[tid] += partial[tid + s];
      __syncthreads();
    }
    int total = partial[0];
    __syncthreads();
    if (total >= MAXN) lo = mid; else hi = mid;
  }
  u32 V = lo;  // value of the 100th largest (sortable bits)

  __shared__ u64 ckey[512];
  __shared__ int cnt2;
  if (tid == 0) cnt2 = 0;
  __syncthreads();
#pragma unroll
  for (int k = 0; k < 63; ++k) {
    int i = tid + k * 256;
    if (i < 16000 && uloc[k] >= V) {
      int p = atomicAdd(&cnt2, 1);
      if (p < 512) ckey[p] = ((u64)uloc[k] << 32) | (u32)(~(u32)i);
    }
  }
  __syncthreads();
  int m2 = min(cnt2, 512);
  for (int i = m2 + tid; i < 512; i += 256) ckey[i] = 0ULL;
  __syncthreads();
  bitonic_desc(ckey, 512, tid);

  __shared__ int selanc[MAXN];
  if (tid < MAXN) {
    u64 kk = ckey[tid];
    u32 u = (u32)(kk >> 32);
    float v = unsortable_f(u);
    u32 flat = ~(u32)(kk & 0xFFFFFFFFULL);
    int ccls = (int)(flat / 200u);
    int an = anc[(size_t)b * 16000 + flat];
    float4 bx = (an >= 0) ? bbox[(size_t)b * NANCH + an] : make_float4(0.f, 0.f, 0.f, 0.f);
    float* dout = out + (size_t)b * 500 + (size_t)tid * 5;
    dout[0] = bx.x; dout[1] = bx.y; dout[2] = bx.z; dout[3] = bx.w; dout[4] = v;
    out[32000 + (size_t)b * 100 + tid] = (float)ccls;  // labels as f32
    selanc[tid] = an;
  }
  __syncthreads();

  float* cp = csel + (size_t)b * 3200;
  for (int idx = tid; idx < 3200; idx += 256) {
    int kk = idx >> 5, q = idx & 31;
    int an = selanc[kk];
    float cv = 0.f;
    if (an >= 0) {
      if (an < 4800)      { int rel = an;        int hw = rel / 3, a = rel % 3; cv = f0[((size_t)b * 96 + (size_t)(a * 32 + q)) * 1600 + hw]; }
      else if (an < 6000) { int rel = an - 4800; int hw = rel / 3, a = rel % 3; cv = f1[((size_t)b * 96 + (size_t)(a * 32 + q)) * 400 + hw]; }
      else if (an < 6300) { int rel = an - 6000; int hw = rel / 3, a = rel % 3; cv = f2[((size_t)b * 96 + (size_t)(a * 32 + q)) * 100 + hw]; }
      else if (an < 6375) { int rel = an - 6300; int hw = rel / 3, a = rel % 3; cv = f3[((size_t)b * 96 + (size_t)(a * 32 + q)) * 25 + hw]; }
      else                { int rel = an - 6375; int hw = rel / 3, a = rel % 3; cv = f4[((size_t)b * 96 + (size_t)(a * 32 + q)) * 9 + hw]; }
    }
    cp[idx] = cv;
  }
}

// ---------- kernel 4: masks = sigmoid(proto @ cselT) ----------
__global__ __launch_bounds__(256) void k_mask(const float* __restrict__ proto,
                                              const float* __restrict__ csel,
                                              float* __restrict__ outm) {
  __shared__ __align__(16) float S[100 * 36];   // padded stride 36 -> f4-aligned, conflict-free
  __shared__ float Pt[128 * 33];                // padded stride 33 -> conflict-free
  int bid = blockIdx.x;
  int b = bid / 50, tile = bid - b * 50;
  int tid = threadIdx.x;

  const float* cs = csel + (size_t)b * 3200;
  for (int i = tid; i < 3200; i += 256) {
    int n = i >> 5, j = i & 31;
    S[n * 36 + j] = cs[i];
  }
  const float* pp = proto + (size_t)b * 204800 + (size_t)tile * 4096;
  for (int i = tid; i < 4096; i += 256) {
    int r = i >> 5, j = i & 31;
    Pt[r * 33 + j] = pp[i];
  }
  __syncthreads();

  int q = tid & 3, r = tid >> 2;  // r in [0,64): rows r and r+64; q picks 25-col chunk
  float p0[32], p1[32];
#pragma unroll
  for (int j = 0; j < 32; ++j) { p0[j] = Pt[r * 33 + j]; p1[j] = Pt[(r + 64) * 33 + j]; }

  float* o0 = outm + (size_t)b * 640000 + (size_t)(tile * 128 + r) * 100 + q * 25;
  float* o1 = o0 + 6400;
  for (int i = 0; i < 25; ++i) {
    int n = q * 25 + i;
    const float4* sp = (const float4*)&S[n * 36];
    float a0 = 0.f, a1 = 0.f;
#pragma unroll
    for (int jc = 0; jc < 8; ++jc) {
      float4 sv = sp[jc];
      a0 += p0[jc * 4 + 0] * sv.x; a1 += p1[jc * 4 + 0] * sv.x;
      a0 += p0[jc * 4 + 1] * sv.y; a1 += p1[jc * 4 + 1] * sv.y;
      a0 += p0[jc * 4 + 2] * sv.z; a1 += p1[jc * 4 + 2] * sv.z;
      a0 += p0[jc * 4 + 3] * sv.w; a1 += p1[jc * 4 + 3] * sv.w;
    }
    o0[i] = 1.f / (1.f + expf(-a0));
    o1[i] = 1.f / (1.f + expf(-a1));
  }
}

// ---------- launch ----------
extern "C" void kernel_launch(void* const* d_in, const int* in_sizes, int n_in,
                              void* d_out, int out_size, void* d_ws, size_t ws_size,
                              hipStream_t stream) {
  const float* c0 = (const float*)d_in[0];
  const float* c1 = (const float*)d_in[1];
  const float* c2 = (const float*)d_in[2];
  const float* c3 = (const float*)d_in[3];
  const float* c4 = (const float*)d_in[4];
  const float* b0 = (const float*)d_in[5];
  const float* b1 = (const float*)d_in[6];
  const float* b2 = (const float*)d_in[7];
  const float* b3 = (const float*)d_in[8];
  const float* b4 = (const float*)d_in[9];
  const float* f0 = (const float*)d_in[10];
  const float* f1 = (const float*)d_in[11];
  const float* f2 = (const float*)d_in[12];
  const float* f3 = (const float*)d_in[13];
  const float* f4 = (const float*)d_in[14];
  const float* proto = (const float*)d_in[15];
  float* out = (float*)d_out;

  float* w = (float*)d_ws;
  // workspace layout (float units):
  // bbox: [0, 1638912)  = 64*6402*4
  // thr:  [1638912, 2048640) = 64*6402   (replaces old float2 md; rest of region unused)
  // val:  [2458368, 3482368) = 64*16000
  // anc:  [3482368, 4506368) = 64*16000 (int)
  // csel: [4506368, 4711168) = 64*100*32
  float4* bbox = (float4*)w;
  float* thr = w + 1638912;
  float* val = w + 2458368;
  int* anc = (int*)(w + 3482368);
  float* csel = w + 4506368;

  k_prep<<<1601, 256, 0, stream>>>(c0, c1, c2, c3, c4, b0, b1, b2, b3, b4, thr, bbox);
  k_nms<<<64 * NCLS, 256, 0, stream>>>(c0, c1, c2, c3, c4, thr, bbox, val, anc);
  k_top<<<64, 256, 0, stream>>>(val, anc, bbox, f0, f1, f2, f3, f4, out, csel);
  k_mask<<<64 * 50, 256, 0, stream>>>(proto, csel, out + 38400);
}

// Round 3
// 771.029 us; speedup vs baseline: 1.0436x; 1.0156x over previous
//
#include <hip/hip_runtime.h>
#include <math.h>

typedef unsigned int u32;
typedef unsigned long long u64;

#define NANCH 6402
#define THRS 6404   // padded per-batch stride for thr (keeps float4 reads 16B-aligned)
#define NCLS 80
#define TOPK 200
#define MAXN 100

// ---------- helpers ----------
__device__ __forceinline__ u32 sortable_u32(float f) {
  u32 u = __float_as_uint(f);
  return u ^ ((u32)(((int)u) >> 31) | 0x80000000u);
}
__device__ __forceinline__ float unsortable_f(u32 u) {
  u32 f = (u & 0x80000000u) ? (u ^ 0x80000000u) : ~u;
  return __uint_as_float(f);
}

__device__ __forceinline__ u64 shfl_xor_u64(u64 v, int m) {
  u32 lo = (u32)__shfl_xor((int)(u32)(v & 0xFFFFFFFFULL), m, 64);
  u32 hi = (u32)__shfl_xor((int)(u32)(v >> 32), m, 64);
  return ((u64)hi << 32) | lo;
}

// descending bitonic sort of P (power of 2) u64 keys in LDS, 256 threads
// (fallback path only; common path uses the register/shuffle sort below)
__device__ void bitonic_desc(u64* keys, int P, int tid) {
  for (int k = 2; k <= P; k <<= 1) {
    for (int j = k >> 1; j > 0; j >>= 1) {
      for (int i = tid; i < P; i += 256) {
        int l = i ^ j;
        if (l > i) {
          u64 a = keys[i], b = keys[l];
          bool desc = ((i & k) == 0);
          if (desc ? (a < b) : (a > b)) { keys[i] = b; keys[l] = a; }
        }
      }
      __syncthreads();
    }
  }
}

// ---------- kernel 1: softmax threshold precompute + bbox decode ----------
// thr = m + log(0.05 * den)  =>  (score > 0.05) <=> (logit > thr),
// and score = 0.05 * exp(logit - thr) (monotone, ~1e-7 rel of exp(l-m)/den).
template<int W, int HW, int BS, int OFF>
__device__ void prep_level(int t, const float* __restrict__ cls,
                           const float* __restrict__ box,
                           float* __restrict__ thr, float4* __restrict__ bbox) {
  if (t >= 64 * 3 * HW) return;
  int b = t / (3 * HW);
  int rem = t - b * 3 * HW;
  int a = rem / HW;
  int hw = rem - a * HW;

  const float* cbase = cls + ((size_t)b * 243 + (size_t)a * 81) * HW + hw;
  float m = cbase[0];
#pragma unroll 4
  for (int c = 1; c < 81; ++c) m = fmaxf(m, cbase[(size_t)c * HW]);
  double den = 0.0;
#pragma unroll 4
  for (int c = 0; c < 81; ++c) den += (double)expf(cbase[(size_t)c * HW] - m);
  // plane-major layout: p = OFF + a*HW + hw  (coalesced re-read in k_compact)
  thr[(size_t)b * THRS + OFF + a * HW + hw] = m + logf(0.05f * (float)den);

  // bbox decode
  const float* bb = box + ((size_t)b * 12 + (size_t)a * 4) * HW + hw;
  float d0 = bb[0] * 0.1f;
  float d1 = bb[HW] * 0.1f;
  float d2 = bb[2 * HW] * 0.2f;
  float d3 = bb[3 * HW] * 0.2f;
  const float MR = 4.135166556742356f;  // |log(0.016)| cast to f32
  d2 = fminf(fmaxf(d2, -MR), MR);
  d3 = fminf(fmaxf(d3, -MR), MR);

  int x = hw % W, y = hw / W;
  double r = (a == 0) ? 0.5 : ((a == 1) ? 1.0 : 2.0);
  double hr = sqrt(r), wr = 1.0 / hr;
  double wsd = ((double)BS * wr) * 3.0;
  double hsd = ((double)BS * hr) * 3.0;
  double cc = (double)BS * 0.5;
  double sx = (double)(x * BS), sy = (double)(y * BS);
  float ax0 = (float)((cc - 0.5 * wsd) + sx);
  float ay0 = (float)((cc - 0.5 * hsd) + sy);
  float ax1 = (float)((cc + 0.5 * wsd) + sx);
  float ay1 = (float)((cc + 0.5 * hsd) + sy);

  float px = (ax0 + ax1) * 0.5f, py = (ay0 + ay1) * 0.5f;
  float pw = ax1 - ax0, ph = ay1 - ay0;
  float gx = px + pw * d0, gy = py + ph * d1;
  float gw = pw * expf(d2), gh = ph * expf(d3);
  float x0 = fminf(fmaxf(gx - 0.5f * gw, 0.f), 320.f);
  float y0 = fminf(fmaxf(gy - 0.5f * gh, 0.f), 320.f);
  float x1 = fminf(fmaxf(gx + 0.5f * gw, 0.f), 320.f);
  float y1 = fminf(fmaxf(gy + 0.5f * gh, 0.f), 320.f);
  int n = OFF + hw * 3 + a;  // anchor-major index (matches reference flatten)
  bbox[(size_t)b * NANCH + n] = make_float4(x0, y0, x1, y1);
}

__global__ __launch_bounds__(256) void k_prep(
    const float* c0, const float* c1, const float* c2, const float* c3, const float* c4,
    const float* b0, const float* b1, const float* b2, const float* b3, const float* b4,
    float* thr, float4* bbox) {
  int bid = blockIdx.x, tid = threadIdx.x;
  if (bid < 1200)      prep_level<40, 1600, 8, 0>(bid * 256 + tid, c0, b0, thr, bbox);
  else if (bid < 1500) prep_level<20, 400, 16, 4800>((bid - 1200) * 256 + tid, c1, b1, thr, bbox);
  else if (bid < 1575) prep_level<10, 100, 32, 6000>((bid - 1500) * 256 + tid, c2, b2, thr, bbox);
  else if (bid < 1594) prep_level<5, 25, 64, 6300>((bid - 1575) * 256 + tid, c3, b3, thr, bbox);
  else                 prep_level<3, 9, 128, 6375>((bid - 1594) * 256 + tid, c4, b4, thr, bbox);
}

// ---------- kernel 2a: per-(batch,class) candidate compact + top-200 sort ----------
// vectorized scan (HW divisible by 4): float4 logit + float4 thr per lane
template<int HW, int OFF>
__device__ void compact_level_v(int b, int ccls, const float* __restrict__ cls,
                                const float* __restrict__ thr,
                                u64* keys, int* cnt, int tid) {
  const int NF4 = 3 * HW / 4;
  for (int idx = tid; idx < NF4; idx += 256) {
    int a = idx / (HW / 4);
    int h4 = idx - a * (HW / 4);
    float4 lv = ((const float4*)(cls + ((size_t)b * 243 + (size_t)a * 81 + ccls) * HW))[h4];
    float4 tv = ((const float4*)(thr + (size_t)b * THRS + OFF + a * HW))[h4];
    int hwb = h4 * 4;
#define CAND(le, te, ei)                                            \
    if ((le) > (te)) {                                              \
      float s = 0.05f * expf((le) - (te));                          \
      int pos = atomicAdd(cnt, 1);                                  \
      if (pos < 1024) {                                             \
        u32 n = (u32)(OFF + (hwb + (ei)) * 3 + a);                  \
        keys[pos] = ((u64)__float_as_uint(s) << 32) | (u32)(~n);    \
      }                                                             \
    }
    CAND(lv.x, tv.x, 0)
    CAND(lv.y, tv.y, 1)
    CAND(lv.z, tv.z, 2)
    CAND(lv.w, tv.w, 3)
#undef CAND
  }
}

// scalar scan for the tiny levels (HW = 25, 9)
template<int HW, int OFF>
__device__ void compact_level_s(int b, int ccls, const float* __restrict__ cls,
                                const float* __restrict__ thr,
                                u64* keys, int* cnt, int tid) {
  for (int a = 0; a < 3; ++a) {
    const float* src = cls + ((size_t)b * 243 + (size_t)a * 81 + ccls) * HW;
    const float* tp = thr + (size_t)b * THRS + OFF + a * HW;
    for (int hw = tid; hw < HW; hw += 256) {
      float l = src[hw];
      float t = tp[hw];
      if (l > t) {
        float s = 0.05f * expf(l - t);
        int pos = atomicAdd(cnt, 1);
        if (pos < 1024) {
          u32 n = (u32)(OFF + hw * 3 + a);
          keys[pos] = ((u64)__float_as_uint(s) << 32) | (u32)(~n);
        }
      }
    }
  }
}

__global__ __launch_bounds__(256) void k_compact(
    const float* c0, const float* c1, const float* c2, const float* c3, const float* c4,
    const float* __restrict__ thr,
    float* __restrict__ val, int* __restrict__ anc) {
  __shared__ u64 keys[1024];
  __shared__ int cnt;
  int tid = threadIdx.x;
  int bid = blockIdx.x;
  int b = bid / NCLS;
  int ccls = bid - b * NCLS;
  if (tid == 0) cnt = 0;
  __syncthreads();

  compact_level_v<1600, 0>(b, ccls, c0, thr, keys, &cnt, tid);
  compact_level_v<400, 4800>(b, ccls, c1, thr, keys, &cnt, tid);
  compact_level_v<100, 6000>(b, ccls, c2, thr, keys, &cnt, tid);
  compact_level_s<25, 6300>(b, ccls, c3, thr, keys, &cnt, tid);
  compact_level_s<9, 6375>(b, ccls, c4, thr, keys, &cnt, tid);
  __syncthreads();

  int cntc = min(cnt, 1024);
  float* valp = val + (size_t)b * (NCLS * TOPK) + (size_t)ccls * TOPK;
  int* ancp = anc + (size_t)b * (NCLS * TOPK) + (size_t)ccls * TOPK;

  if (cntc <= 256) {
    // fast path (~90% of blocks): in-register bitonic-256, one key/thread.
    // 33 intra-wave stages via shfl_xor (no barriers), 3 cross-wave via LDS.
    u64 key = (tid < cntc) ? keys[tid] : 0ULL;
    for (int k = 2; k <= 256; k <<= 1) {
      for (int j = k >> 1; j > 0; j >>= 1) {
        bool lower = ((tid & j) == 0);
        bool desc = ((tid & k) == 0);
        u64 o;
        if (j >= 64) {
          keys[tid] = key;
          __syncthreads();
          o = keys[tid ^ j];
          __syncthreads();
        } else {
          o = shfl_xor_u64(key, j);
        }
        bool take_max = (lower == desc);
        key = (take_max ? (key >= o) : (key <= o)) ? key : o;
      }
    }
    int K2 = min(cntc, TOPK);
    if (tid < TOPK) {
      if (tid < K2) {
        valp[tid] = __uint_as_float((u32)(key >> 32));
        ancp[tid] = (int)(~(u32)key);
      } else {
        valp[tid] = -1.0f;
        ancp[tid] = -1;
      }
    }
  } else {
    // rare fallback: LDS bitonic on 512/1024
    int P = (cntc <= 512) ? 512 : 1024;
    for (int i = cntc + tid; i < P; i += 256) keys[i] = 0ULL;
    __syncthreads();
    bitonic_desc(keys, P, tid);
    int K2 = min(cntc, TOPK);
    if (tid < TOPK) {
      if (tid < K2) {
        u64 kk = keys[tid];
        valp[tid] = __uint_as_float((u32)(kk >> 32));
        ancp[tid] = (int)(~(u32)kk);
      } else {
        valp[tid] = -1.0f;
        ancp[tid] = -1;
      }
    }
  }
}

// ---------- kernel 2b: per-(batch,class) Fast NMS on the sorted top-200 ----------
__global__ __launch_bounds__(256) void k_fastnms(
    const float4* __restrict__ bbox,
    float* __restrict__ val, const int* __restrict__ anc) {
  __shared__ float4 boxes[TOPK];
  __shared__ float area[TOPK];
  __shared__ u32 suppw[8];
  __shared__ int k2s;
  int tid = threadIdx.x;
  int bid = blockIdx.x;
  int b = bid / NCLS;
  int ccls = bid - b * NCLS;
  if (tid == 0) k2s = TOPK;
  if (tid < 8) suppw[tid] = 0u;
  __syncthreads();

  float* valp = val + (size_t)b * (NCLS * TOPK) + (size_t)ccls * TOPK;
  const int* ancp = anc + (size_t)b * (NCLS * TOPK) + (size_t)ccls * TOPK;

  if (tid < TOPK) {
    int an = ancp[tid];
    if (an >= 0) {
      float4 bx = bbox[(size_t)b * NANCH + an];
      boxes[tid] = bx;
      area[tid] = (bx.z - bx.x) * (bx.w - bx.y);
    } else {
      atomicMin(&k2s, tid);
    }
  }
  __syncthreads();
  int K2 = k2s;

  // balanced pair-parallel Fast-NMS:
  //   supp[j] = OR_{i<j} (iou(i,j) > 0.5)   (order-free)
  // thread t: columns {pn, K2-1-pn}, i-range parity-split by half;
  // i is wave-uniform per iteration -> boxes[i]/area[i] are LDS broadcasts.
  {
    int pn = tid & 127;
    int half = tid >> 7;
    for (int rep = 0; rep < 2; ++rep) {
      int j = rep ? (K2 - 1 - pn) : pn;
      if (rep && j == pn) break;     // same column, rep0 already did it (both halves)
      if (j < 1 || j >= K2) continue;
      float4 bj = boxes[j];
      float aj = area[j];
      bool sup = false;
      for (int i = half; i < j; i += 2) {
        float4 bi = boxes[i];
        float wx = fmaxf(fminf(bi.z, bj.z) - fmaxf(bi.x, bj.x), 0.f);
        float wy = fmaxf(fminf(bi.w, bj.w) - fmaxf(bi.y, bj.y), 0.f);
        float ov = wx * wy;
        float un = fmaxf(area[i] + aj - ov, 1e-6f);
        bool sp;
        if (ov > un * 0.505f) sp = true;                  // certainly iou > 0.5
        else if (ov > un * 0.495f) sp = (ov / un > 0.5f); // exact IEEE division
        else sp = false;
        if (sp) { sup = true; break; }
      }
      if (sup) atomicOr(&suppw[j >> 5], 1u << (j & 31));
    }
  }
  __syncthreads();

  // scatter-write -1 only for suppressed entries (val already holds scores)
  if (tid < K2) {
    if ((suppw[tid >> 5] >> (tid & 31)) & 1u) valp[tid] = -1.0f;
  }
}

// ---------- kernel 3: per-batch global top-100 + dets/labels/coeff gather ----------
__global__ __launch_bounds__(256) void k_top(
    const float* __restrict__ val, const int* __restrict__ anc,
    const float4* __restrict__ bbox,
    const float* f0, const float* f1, const float* f2, const float* f3, const float* f4,
    float* __restrict__ out, float* __restrict__ csel) {
  int b = blockIdx.x, tid = threadIdx.x;
  const float* vp = val + (size_t)b * 16000;

  u32 uloc[63];
#pragma unroll
  for (int k = 0; k < 63; ++k) {
    int i = tid + k * 256;
    uloc[k] = (i < 16000) ? sortable_u32(vp[i]) : 0u;
  }

  __shared__ int partial[256];
  u32 lo = 0u, hi = 0xFFFFFFFFu;
  for (int it = 0; it < 32; ++it) {
    u32 mid = lo + ((hi - lo) >> 1);
    int cme = 0;
#pragma unroll
    for (int k = 0; k < 63; ++k) cme += (uloc[k] >= mid) ? 1 : 0;
    partial[tid] = cme;
    __syncthreads();
    for (int s = 128; s > 0; s >>= 1) {
      if (tid < s) partial[tid] += partial[tid + s];
      __syncthreads();
    }
    int total = partial[0];
    __syncthreads();
    if (total >= MAXN) lo = mid; else hi = mid;
  }
  u32 V = lo;  // value of the 100th largest (sortable bits)

  __shared__ u64 ckey[512];
  __shared__ int cnt2;
  if (tid == 0) cnt2 = 0;
  __syncthreads();
#pragma unroll
  for (int k = 0; k < 63; ++k) {
    int i = tid + k * 256;
    if (i < 16000 && uloc[k] >= V) {
      int p = atomicAdd(&cnt2, 1);
      if (p < 512) ckey[p] = ((u64)uloc[k] << 32) | (u32)(~(u32)i);
    }
  }
  __syncthreads();
  int m2 = min(cnt2, 512);
  for (int i = m2 + tid; i < 512; i += 256) ckey[i] = 0ULL;
  __syncthreads();
  bitonic_desc(ckey, 512, tid);

  __shared__ int selanc[MAXN];
  if (tid < MAXN) {
    u64 kk = ckey[tid];
    u32 u = (u32)(kk >> 32);
    float v = unsortable_f(u);
    u32 flat = ~(u32)(kk & 0xFFFFFFFFULL);
    int ccls = (int)(flat / 200u);
    int an = anc[(size_t)b * 16000 + flat];
    float4 bx = (an >= 0) ? bbox[(size_t)b * NANCH + an] : make_float4(0.f, 0.f, 0.f, 0.f);
    float* dout = out + (size_t)b * 500 + (size_t)tid * 5;
    dout[0] = bx.x; dout[1] = bx.y; dout[2] = bx.z; dout[3] = bx.w; dout[4] = v;
    out[32000 + (size_t)b * 100 + tid] = (float)ccls;  // labels as f32
    selanc[tid] = an;
  }
  __syncthreads();

  float* cp = csel + (size_t)b * 3200;
  for (int idx = tid; idx < 3200; idx += 256) {
    int kk = idx >> 5, q = idx & 31;
    int an = selanc[kk];
    float cv = 0.f;
    if (an >= 0) {
      if (an < 4800)      { int rel = an;        int hw = rel / 3, a = rel % 3; cv = f0[((size_t)b * 96 + (size_t)(a * 32 + q)) * 1600 + hw]; }
      else if (an < 6000) { int rel = an - 4800; int hw = rel / 3, a = rel % 3; cv = f1[((size_t)b * 96 + (size_t)(a * 32 + q)) * 400 + hw]; }
      else if (an < 6300) { int rel = an - 6000; int hw = rel / 3, a = rel % 3; cv = f2[((size_t)b * 96 + (size_t)(a * 32 + q)) * 100 + hw]; }
      else if (an < 6375) { int rel = an - 6300; int hw = rel / 3, a = rel % 3; cv = f3[((size_t)b * 96 + (size_t)(a * 32 + q)) * 25 + hw]; }
      else                { int rel = an - 6375; int hw = rel / 3, a = rel % 3; cv = f4[((size_t)b * 96 + (size_t)(a * 32 + q)) * 9 + hw]; }
    }
    cp[idx] = cv;
  }
}

// ---------- kernel 4: masks = sigmoid(proto @ cselT) ----------
__global__ __launch_bounds__(256) void k_mask(const float* __restrict__ proto,
                                              const float* __restrict__ csel,
                                              float* __restrict__ outm) {
  __shared__ __align__(16) float S[100 * 36];   // padded stride 36 -> f4-aligned, conflict-free
  __shared__ float Pt[128 * 33];                // padded stride 33 -> conflict-free
  int bid = blockIdx.x;
  int b = bid / 50, tile = bid - b * 50;
  int tid = threadIdx.x;

  const float* cs = csel + (size_t)b * 3200;
  for (int i = tid; i < 3200; i += 256) {
    int n = i >> 5, j = i & 31;
    S[n * 36 + j] = cs[i];
  }
  const float* pp = proto + (size_t)b * 204800 + (size_t)tile * 4096;
  for (int i = tid; i < 4096; i += 256) {
    int r = i >> 5, j = i & 31;
    Pt[r * 33 + j] = pp[i];
  }
  __syncthreads();

  int q = tid & 3, r = tid >> 2;  // r in [0,64): rows r and r+64; q picks 25-col chunk
  float p0[32], p1[32];
#pragma unroll
  for (int j = 0; j < 32; ++j) { p0[j] = Pt[r * 33 + j]; p1[j] = Pt[(r + 64) * 33 + j]; }

  float* o0 = outm + (size_t)b * 640000 + (size_t)(tile * 128 + r) * 100 + q * 25;
  float* o1 = o0 + 6400;
  for (int i = 0; i < 25; ++i) {
    int n = q * 25 + i;
    const float4* sp = (const float4*)&S[n * 36];
    float a0 = 0.f, a1 = 0.f;
#pragma unroll
    for (int jc = 0; jc < 8; ++jc) {
      float4 sv = sp[jc];
      a0 += p0[jc * 4 + 0] * sv.x; a1 += p1[jc * 4 + 0] * sv.x;
      a0 += p0[jc * 4 + 1] * sv.y; a1 += p1[jc * 4 + 1] * sv.y;
      a0 += p0[jc * 4 + 2] * sv.z; a1 += p1[jc * 4 + 2] * sv.z;
      a0 += p0[jc * 4 + 3] * sv.w; a1 += p1[jc * 4 + 3] * sv.w;
    }
    o0[i] = 1.f / (1.f + expf(-a0));
    o1[i] = 1.f / (1.f + expf(-a1));
  }
}

// ---------- launch ----------
extern "C" void kernel_launch(void* const* d_in, const int* in_sizes, int n_in,
                              void* d_out, int out_size, void* d_ws, size_t ws_size,
                              hipStream_t stream) {
  const float* c0 = (const float*)d_in[0];
  const float* c1 = (const float*)d_in[1];
  const float* c2 = (const float*)d_in[2];
  const float* c3 = (const float*)d_in[3];
  const float* c4 = (const float*)d_in[4];
  const float* b0 = (const float*)d_in[5];
  const float* b1 = (const float*)d_in[6];
  const float* b2 = (const float*)d_in[7];
  const float* b3 = (const float*)d_in[8];
  const float* b4 = (const float*)d_in[9];
  const float* f0 = (const float*)d_in[10];
  const float* f1 = (const float*)d_in[11];
  const float* f2 = (const float*)d_in[12];
  const float* f3 = (const float*)d_in[13];
  const float* f4 = (const float*)d_in[14];
  const float* proto = (const float*)d_in[15];
  float* out = (float*)d_out;

  float* w = (float*)d_ws;
  // workspace layout (float units):
  // bbox: [0, 1638912)  = 64*6402*4
  // thr:  [1638912, 2048768) = 64*6404 (padded stride for f4-aligned reads)
  // val:  [2458368, 3482368) = 64*16000
  // anc:  [3482368, 4506368) = 64*16000 (int)
  // csel: [4506368, 4711168) = 64*100*32
  float4* bbox = (float4*)w;
  float* thr = w + 1638912;
  float* val = w + 2458368;
  int* anc = (int*)(w + 3482368);
  float* csel = w + 4506368;

  k_prep<<<1601, 256, 0, stream>>>(c0, c1, c2, c3, c4, b0, b1, b2, b3, b4, thr, bbox);
  k_compact<<<64 * NCLS, 256, 0, stream>>>(c0, c1, c2, c3, c4, thr, val, anc);
  k_fastnms<<<64 * NCLS, 256, 0, stream>>>(bbox, val, anc);
  k_top<<<64, 256, 0, stream>>>(val, anc, bbox, f0, f1, f2, f3, f4, out, csel);
  k_mask<<<64 * 50, 256, 0, stream>>>(proto, csel, out + 38400);
}

// Round 4
// 708.979 us; speedup vs baseline: 1.1350x; 1.0875x over previous
//
#include <hip/hip_runtime.h>
#include <math.h>

typedef unsigned int u32;
typedef unsigned long long u64;

#define NANCH 6402
#define THRS 6404   // padded per-batch stride for thr (keeps float4 reads 16B-aligned)
#define NCLS 80
#define TOPK 200
#define MAXN 100

// ---------- helpers ----------
__device__ __forceinline__ u32 sortable_u32(float f) {
  u32 u = __float_as_uint(f);
  return u ^ ((u32)(((int)u) >> 31) | 0x80000000u);
}
__device__ __forceinline__ float unsortable_f(u32 u) {
  u32 f = (u & 0x80000000u) ? (u ^ 0x80000000u) : ~u;
  return __uint_as_float(f);
}

__device__ __forceinline__ u64 shfl_xor_u64(u64 v, int m) {
  u32 lo = (u32)__shfl_xor((int)(u32)(v & 0xFFFFFFFFULL), m, 64);
  u32 hi = (u32)__shfl_xor((int)(u32)(v >> 32), m, 64);
  return ((u64)hi << 32) | lo;
}

// descending bitonic sort of P (power of 2) u64 keys in LDS, 256 threads
// (fallback path only; common path uses the register/shuffle sort below)
__device__ void bitonic_desc(u64* keys, int P, int tid) {
  for (int k = 2; k <= P; k <<= 1) {
    for (int j = k >> 1; j > 0; j >>= 1) {
      for (int i = tid; i < P; i += 256) {
        int l = i ^ j;
        if (l > i) {
          u64 a = keys[i], b = keys[l];
          bool desc = ((i & k) == 0);
          if (desc ? (a < b) : (a > b)) { keys[i] = b; keys[l] = a; }
        }
      }
      __syncthreads();
    }
  }
}

// ---------- kernel 1: softmax threshold precompute + bbox decode ----------
// thr = m + log(0.05 * den)  =>  (score > 0.05) <=> (logit > thr),
// and score = 0.05 * exp(logit - thr) (monotone, ~1e-7 rel of exp(l-m)/den).
template<int W, int HW, int BS, int OFF>
__device__ void prep_level(int t, const float* __restrict__ cls,
                           const float* __restrict__ box,
                           float* __restrict__ thr, float4* __restrict__ bbox) {
  if (t >= 64 * 3 * HW) return;
  int b = t / (3 * HW);
  int rem = t - b * 3 * HW;
  int a = rem / HW;
  int hw = rem - a * HW;

  const float* cbase = cls + ((size_t)b * 243 + (size_t)a * 81) * HW + hw;
  float m = cbase[0];
#pragma unroll 4
  for (int c = 1; c < 81; ++c) m = fmaxf(m, cbase[(size_t)c * HW]);
  double den = 0.0;
#pragma unroll 4
  for (int c = 0; c < 81; ++c) den += (double)expf(cbase[(size_t)c * HW] - m);
  // plane-major layout: p = OFF + a*HW + hw  (coalesced re-read in k_compact)
  thr[(size_t)b * THRS + OFF + a * HW + hw] = m + logf(0.05f * (float)den);

  // bbox decode
  const float* bb = box + ((size_t)b * 12 + (size_t)a * 4) * HW + hw;
  float d0 = bb[0] * 0.1f;
  float d1 = bb[HW] * 0.1f;
  float d2 = bb[2 * HW] * 0.2f;
  float d3 = bb[3 * HW] * 0.2f;
  const float MR = 4.135166556742356f;  // |log(0.016)| cast to f32
  d2 = fminf(fmaxf(d2, -MR), MR);
  d3 = fminf(fmaxf(d3, -MR), MR);

  int x = hw % W, y = hw / W;
  double r = (a == 0) ? 0.5 : ((a == 1) ? 1.0 : 2.0);
  double hr = sqrt(r), wr = 1.0 / hr;
  double wsd = ((double)BS * wr) * 3.0;
  double hsd = ((double)BS * hr) * 3.0;
  double cc = (double)BS * 0.5;
  double sx = (double)(x * BS), sy = (double)(y * BS);
  float ax0 = (float)((cc - 0.5 * wsd) + sx);
  float ay0 = (float)((cc - 0.5 * hsd) + sy);
  float ax1 = (float)((cc + 0.5 * wsd) + sx);
  float ay1 = (float)((cc + 0.5 * hsd) + sy);

  float px = (ax0 + ax1) * 0.5f, py = (ay0 + ay1) * 0.5f;
  float pw = ax1 - ax0, ph = ay1 - ay0;
  float gx = px + pw * d0, gy = py + ph * d1;
  float gw = pw * expf(d2), gh = ph * expf(d3);
  float x0 = fminf(fmaxf(gx - 0.5f * gw, 0.f), 320.f);
  float y0 = fminf(fmaxf(gy - 0.5f * gh, 0.f), 320.f);
  float x1 = fminf(fmaxf(gx + 0.5f * gw, 0.f), 320.f);
  float y1 = fminf(fmaxf(gy + 0.5f * gh, 0.f), 320.f);
  int n = OFF + hw * 3 + a;  // anchor-major index (matches reference flatten)
  bbox[(size_t)b * NANCH + n] = make_float4(x0, y0, x1, y1);
}

__global__ __launch_bounds__(256) void k_prep(
    const float* c0, const float* c1, const float* c2, const float* c3, const float* c4,
    const float* b0, const float* b1, const float* b2, const float* b3, const float* b4,
    float* thr, float4* bbox) {
  int bid = blockIdx.x, tid = threadIdx.x;
  if (bid < 1200)      prep_level<40, 1600, 8, 0>(bid * 256 + tid, c0, b0, thr, bbox);
  else if (bid < 1500) prep_level<20, 400, 16, 4800>((bid - 1200) * 256 + tid, c1, b1, thr, bbox);
  else if (bid < 1575) prep_level<10, 100, 32, 6000>((bid - 1500) * 256 + tid, c2, b2, thr, bbox);
  else if (bid < 1594) prep_level<5, 25, 64, 6300>((bid - 1575) * 256 + tid, c3, b3, thr, bbox);
  else                 prep_level<3, 9, 128, 6375>((bid - 1594) * 256 + tid, c4, b4, thr, bbox);
}

// ---------- kernel 2a: per-(batch,class) candidate compact + top-200 sort ----------
// vectorized scan (HW divisible by 4): float4 logit + float4 thr per lane
template<int HW, int OFF>
__device__ void compact_level_v(int b, int ccls, const float* __restrict__ cls,
                                const float* __restrict__ thr,
                                u64* keys, int* cnt, int tid) {
  const int NF4 = 3 * HW / 4;
  for (int idx = tid; idx < NF4; idx += 256) {
    int a = idx / (HW / 4);
    int h4 = idx - a * (HW / 4);
    float4 lv = ((const float4*)(cls + ((size_t)b * 243 + (size_t)a * 81 + ccls) * HW))[h4];
    float4 tv = ((const float4*)(thr + (size_t)b * THRS + OFF + a * HW))[h4];
    int hwb = h4 * 4;
#define CAND(le, te, ei)                                            \
    if ((le) > (te)) {                                              \
      float s = 0.05f * expf((le) - (te));                          \
      int pos = atomicAdd(cnt, 1);                                  \
      if (pos < 1024) {                                             \
        u32 n = (u32)(OFF + (hwb + (ei)) * 3 + a);                  \
        keys[pos] = ((u64)__float_as_uint(s) << 32) | (u32)(~n);    \
      }                                                             \
    }
    CAND(lv.x, tv.x, 0)
    CAND(lv.y, tv.y, 1)
    CAND(lv.z, tv.z, 2)
    CAND(lv.w, tv.w, 3)
#undef CAND
  }
}

// scalar scan for the tiny levels (HW = 25, 9)
template<int HW, int OFF>
__device__ void compact_level_s(int b, int ccls, const float* __restrict__ cls,
                                const float* __restrict__ thr,
                                u64* keys, int* cnt, int tid) {
  for (int a = 0; a < 3; ++a) {
    const float* src = cls + ((size_t)b * 243 + (size_t)a * 81 + ccls) * HW;
    const float* tp = thr + (size_t)b * THRS + OFF + a * HW;
    for (int hw = tid; hw < HW; hw += 256) {
      float l = src[hw];
      float t = tp[hw];
      if (l > t) {
        float s = 0.05f * expf(l - t);
        int pos = atomicAdd(cnt, 1);
        if (pos < 1024) {
          u32 n = (u32)(OFF + hw * 3 + a);
          keys[pos] = ((u64)__float_as_uint(s) << 32) | (u32)(~n);
        }
      }
    }
  }
}

__global__ __launch_bounds__(256) void k_compact(
    const float* c0, const float* c1, const float* c2, const float* c3, const float* c4,
    const float* __restrict__ thr,
    float* __restrict__ val, int* __restrict__ anc) {
  __shared__ u64 keys[1024];
  __shared__ int cnt;
  int tid = threadIdx.x;
  int bid = blockIdx.x;
  int b = bid / NCLS;
  int ccls = bid - b * NCLS;
  if (tid == 0) cnt = 0;
  __syncthreads();

  compact_level_v<1600, 0>(b, ccls, c0, thr, keys, &cnt, tid);
  compact_level_v<400, 4800>(b, ccls, c1, thr, keys, &cnt, tid);
  compact_level_v<100, 6000>(b, ccls, c2, thr, keys, &cnt, tid);
  compact_level_s<25, 6300>(b, ccls, c3, thr, keys, &cnt, tid);
  compact_level_s<9, 6375>(b, ccls, c4, thr, keys, &cnt, tid);
  __syncthreads();

  int cntc = min(cnt, 1024);
  float* valp = val + (size_t)b * (NCLS * TOPK) + (size_t)ccls * TOPK;
  int* ancp = anc + (size_t)b * (NCLS * TOPK) + (size_t)ccls * TOPK;

  if (cntc <= 256) {
    // fast path (~90% of blocks): in-register bitonic-256, one key/thread.
    // 33 intra-wave stages via shfl_xor (no barriers), 3 cross-wave via LDS.
    u64 key = (tid < cntc) ? keys[tid] : 0ULL;
    for (int k = 2; k <= 256; k <<= 1) {
      for (int j = k >> 1; j > 0; j >>= 1) {
        bool lower = ((tid & j) == 0);
        bool desc = ((tid & k) == 0);
        u64 o;
        if (j >= 64) {
          keys[tid] = key;
          __syncthreads();
          o = keys[tid ^ j];
          __syncthreads();
        } else {
          o = shfl_xor_u64(key, j);
        }
        bool take_max = (lower == desc);
        key = (take_max ? (key >= o) : (key <= o)) ? key : o;
      }
    }
    int K2 = min(cntc, TOPK);
    if (tid < TOPK) {
      if (tid < K2) {
        valp[tid] = __uint_as_float((u32)(key >> 32));
        ancp[tid] = (int)(~(u32)key);
      } else {
        valp[tid] = -1.0f;
        ancp[tid] = -1;
      }
    }
  } else {
    // rare fallback: LDS bitonic on 512/1024
    int P = (cntc <= 512) ? 512 : 1024;
    for (int i = cntc + tid; i < P; i += 256) keys[i] = 0ULL;
    __syncthreads();
    bitonic_desc(keys, P, tid);
    int K2 = min(cntc, TOPK);
    if (tid < TOPK) {
      if (tid < K2) {
        u64 kk = keys[tid];
        valp[tid] = __uint_as_float((u32)(kk >> 32));
        ancp[tid] = (int)(~(u32)kk);
      } else {
        valp[tid] = -1.0f;
        ancp[tid] = -1;
      }
    }
  }
}

// ---------- kernel 2b: per-(batch,class) Fast NMS on the sorted top-200 ----------
__global__ __launch_bounds__(256) void k_fastnms(
    const float4* __restrict__ bbox,
    float* __restrict__ val, const int* __restrict__ anc) {
  __shared__ float4 boxes[TOPK];
  __shared__ float area[TOPK];
  __shared__ u32 suppw[8];
  __shared__ int k2s;
  int tid = threadIdx.x;
  int bid = blockIdx.x;
  int b = bid / NCLS;
  int ccls = bid - b * NCLS;
  if (tid == 0) k2s = TOPK;
  if (tid < 8) suppw[tid] = 0u;
  __syncthreads();

  float* valp = val + (size_t)b * (NCLS * TOPK) + (size_t)ccls * TOPK;
  const int* ancp = anc + (size_t)b * (NCLS * TOPK) + (size_t)ccls * TOPK;

  if (tid < TOPK) {
    int an = ancp[tid];
    if (an >= 0) {
      float4 bx = bbox[(size_t)b * NANCH + an];
      boxes[tid] = bx;
      area[tid] = (bx.z - bx.x) * (bx.w - bx.y);
    } else {
      atomicMin(&k2s, tid);
    }
  }
  __syncthreads();
  int K2 = k2s;

  // balanced pair-parallel Fast-NMS:
  //   supp[j] = OR_{i<j} (iou(i,j) > 0.5)   (order-free)
  // thread t: columns {pn, K2-1-pn}, i-range parity-split by half;
  // i is wave-uniform per iteration -> boxes[i]/area[i] are LDS broadcasts.
  {
    int pn = tid & 127;
    int half = tid >> 7;
    for (int rep = 0; rep < 2; ++rep) {
      int j = rep ? (K2 - 1 - pn) : pn;
      if (rep && j == pn) break;     // same column, rep0 already did it (both halves)
      if (j < 1 || j >= K2) continue;
      float4 bj = boxes[j];
      float aj = area[j];
      bool sup = false;
      for (int i = half; i < j; i += 2) {
        float4 bi = boxes[i];
        float wx = fmaxf(fminf(bi.z, bj.z) - fmaxf(bi.x, bj.x), 0.f);
        float wy = fmaxf(fminf(bi.w, bj.w) - fmaxf(bi.y, bj.y), 0.f);
        float ov = wx * wy;
        float un = fmaxf(area[i] + aj - ov, 1e-6f);
        bool sp;
        if (ov > un * 0.505f) sp = true;                  // certainly iou > 0.5
        else if (ov > un * 0.495f) sp = (ov / un > 0.5f); // exact IEEE division
        else sp = false;
        if (sp) { sup = true; break; }
      }
      if (sup) atomicOr(&suppw[j >> 5], 1u << (j & 31));
    }
  }
  __syncthreads();

  // scatter-write -1 only for suppressed entries (val already holds scores)
  if (tid < K2) {
    if ((suppw[tid >> 5] >> (tid & 31)) & 1u) valp[tid] = -1.0f;
  }
}

// ---------- kernel 3: per-batch global top-100 + dets/labels/coeff gather ----------
__global__ __launch_bounds__(256) void k_top(
    const float* __restrict__ val, const int* __restrict__ anc,
    const float4* __restrict__ bbox,
    const float* f0, const float* f1, const float* f2, const float* f3, const float* f4,
    float* __restrict__ out, float* __restrict__ csel) {
  int b = blockIdx.x, tid = threadIdx.x;
  const float* vp = val + (size_t)b * 16000;

  u32 uloc[63];
#pragma unroll
  for (int k = 0; k < 63; ++k) {
    int i = tid + k * 256;
    uloc[k] = (i < 16000) ? sortable_u32(vp[i]) : 0u;
  }

  __shared__ int partial[256];
  u32 lo = 0u, hi = 0xFFFFFFFFu;
  for (int it = 0; it < 32; ++it) {
    u32 mid = lo + ((hi - lo) >> 1);
    int cme = 0;
#pragma unroll
    for (int k = 0; k < 63; ++k) cme += (uloc[k] >= mid) ? 1 : 0;
    partial[tid] = cme;
    __syncthreads();
    for (int s = 128; s > 0; s >>= 1) {
      if (tid < s) partial[tid] += partial[tid + s];
      __syncthreads();
    }
    int total = partial[0];
    __syncthreads();
    if (total >= MAXN) lo = mid; else hi = mid;
  }
  u32 V = lo;  // value of the 100th largest (sortable bits)

  __shared__ u64 ckey[512];
  __shared__ int cnt2;
  if (tid == 0) cnt2 = 0;
  __syncthreads();
#pragma unroll
  for (int k = 0; k < 63; ++k) {
    int i = tid + k * 256;
    if (i < 16000 && uloc[k] >= V) {
      int p = atomicAdd(&cnt2, 1);
      if (p < 512) ckey[p] = ((u64)uloc[k] << 32) | (u32)(~(u32)i);
    }
  }
  __syncthreads();
  int m2 = min(cnt2, 512);
  for (int i = m2 + tid; i < 512; i += 256) ckey[i] = 0ULL;
  __syncthreads();
  bitonic_desc(ckey, 512, tid);

  __shared__ int selanc[MAXN];
  if (tid < MAXN) {
    u64 kk = ckey[tid];
    u32 u = (u32)(kk >> 32);
    float v = unsortable_f(u);
    u32 flat = ~(u32)(kk & 0xFFFFFFFFULL);
    int ccls = (int)(flat / 200u);
    int an = anc[(size_t)b * 16000 + flat];
    float4 bx = (an >= 0) ? bbox[(size_t)b * NANCH + an] : make_float4(0.f, 0.f, 0.f, 0.f);
    float* dout = out + (size_t)b * 500 + (size_t)tid * 5;
    dout[0] = bx.x; dout[1] = bx.y; dout[2] = bx.z; dout[3] = bx.w; dout[4] = v;
    out[32000 + (size_t)b * 100 + tid] = (float)ccls;  // labels as f32
    selanc[tid] = an;
  }
  __syncthreads();

  float* cp = csel + (size_t)b * 3200;
  for (int idx = tid; idx < 3200; idx += 256) {
    int kk = idx >> 5, q = idx & 31;
    int an = selanc[kk];
    float cv = 0.f;
    if (an >= 0) {
      if (an < 4800)      { int rel = an;        int hw = rel / 3, a = rel % 3; cv = f0[((size_t)b * 96 + (size_t)(a * 32 + q)) * 1600 + hw]; }
      else if (an < 6000) { int rel = an - 4800; int hw = rel / 3, a = rel % 3; cv = f1[((size_t)b * 96 + (size_t)(a * 32 + q)) * 400 + hw]; }
      else if (an < 6300) { int rel = an - 6000; int hw = rel / 3, a = rel % 3; cv = f2[((size_t)b * 96 + (size_t)(a * 32 + q)) * 100 + hw]; }
      else if (an < 6375) { int rel = an - 6300; int hw = rel / 3, a = rel % 3; cv = f3[((size_t)b * 96 + (size_t)(a * 32 + q)) * 25 + hw]; }
      else                { int rel = an - 6375; int hw = rel / 3, a = rel % 3; cv = f4[((size_t)b * 96 + (size_t)(a * 32 + q)) * 9 + hw]; }
    }
    cp[idx] = cv;
  }
}

// ---------- kernel 4: masks = sigmoid(proto @ cselT) ----------
// v2: LDS-staged output -> fully coalesced float4 global stores (fixes the
// 2.5x HBM write amplification seen as WRITE_SIZE 410MB vs 164MB ideal).
// proto rows go global->reg directly (q-lanes share a row -> HW broadcast).
#define STG 116   // staging row stride (floats): 116*4B % 16 == 0, 116%32=20 -> conflict-free writes
__global__ __launch_bounds__(256) void k_mask(const float* __restrict__ proto,
                                              const float* __restrict__ csel,
                                              float* __restrict__ outm) {
  __shared__ __align__(16) float S[100 * 36];     // csel, padded stride 36
  __shared__ __align__(16) float stage[64 * STG]; // 29696 B half-tile staging
  int bid = blockIdx.x;
  int b = bid / 50, tile = bid - b * 50;
  int tid = threadIdx.x;

  const float* cs = csel + (size_t)b * 3200;
  for (int i = tid; i < 3200; i += 256) {
    int n = i >> 5, j = i & 31;
    S[n * 36 + j] = cs[i];
  }

  int q = tid & 3, r = tid >> 2;  // r in [0,64): rows r and r+64; q picks 25-col chunk
  const float* pp = proto + (size_t)b * 204800 + (size_t)tile * 4096;
  float p0[32], p1[32];
  const float4* pr0 = (const float4*)(pp + (size_t)r * 32);
  const float4* pr1 = (const float4*)(pp + (size_t)(r + 64) * 32);
#pragma unroll
  for (int jc = 0; jc < 8; ++jc) {
    float4 v0 = pr0[jc];
    p0[jc * 4 + 0] = v0.x; p0[jc * 4 + 1] = v0.y; p0[jc * 4 + 2] = v0.z; p0[jc * 4 + 3] = v0.w;
    float4 v1 = pr1[jc];
    p1[jc * 4 + 0] = v1.x; p1[jc * 4 + 1] = v1.y; p1[jc * 4 + 2] = v1.z; p1[jc * 4 + 3] = v1.w;
  }
  __syncthreads();  // S ready

  float* ob = outm + (size_t)b * 640000 + (size_t)tile * 12800;

  // ---- phase A: rows 0..63 ----
  for (int i = 0; i < 25; ++i) {
    int n = q * 25 + i;
    const float4* sp = (const float4*)&S[n * 36];
    float a0 = 0.f;
#pragma unroll
    for (int jc = 0; jc < 8; ++jc) {
      float4 sv = sp[jc];
      a0 += p0[jc * 4 + 0] * sv.x;
      a0 += p0[jc * 4 + 1] * sv.y;
      a0 += p0[jc * 4 + 2] * sv.z;
      a0 += p0[jc * 4 + 3] * sv.w;
    }
    stage[r * STG + n] = 1.f / (1.f + expf(-a0));
  }
  __syncthreads();
  // coalesced copy: 64 rows * 100 floats = 1600 float4, lane-linear addresses
  for (int f4i = tid; f4i < 1600; f4i += 256) {
    int f = f4i * 4;
    int row = f / 100, col = f - row * 100;   // 100 % 4 == 0 -> chunk stays in-row
    float4 v = *(const float4*)&stage[row * STG + col];
    ((float4*)ob)[f4i] = v;
  }
  __syncthreads();  // stage reuse

  // ---- phase B: rows 64..127 ----
  for (int i = 0; i < 25; ++i) {
    int n = q * 25 + i;
    const float4* sp = (const float4*)&S[n * 36];
    float a1 = 0.f;
#pragma unroll
    for (int jc = 0; jc < 8; ++jc) {
      float4 sv = sp[jc];
      a1 += p1[jc * 4 + 0] * sv.x;
      a1 += p1[jc * 4 + 1] * sv.y;
      a1 += p1[jc * 4 + 2] * sv.z;
      a1 += p1[jc * 4 + 3] * sv.w;
    }
    stage[r * STG + n] = 1.f / (1.f + expf(-a1));
  }
  __syncthreads();
  float* ob1 = ob + 6400;
  for (int f4i = tid; f4i < 1600; f4i += 256) {
    int f = f4i * 4;
    int row = f / 100, col = f - row * 100;
    float4 v = *(const float4*)&stage[row * STG + col];
    ((float4*)ob1)[f4i] = v;
  }
}

// ---------- launch ----------
extern "C" void kernel_launch(void* const* d_in, const int* in_sizes, int n_in,
                              void* d_out, int out_size, void* d_ws, size_t ws_size,
                              hipStream_t stream) {
  const float* c0 = (const float*)d_in[0];
  const float* c1 = (const float*)d_in[1];
  const float* c2 = (const float*)d_in[2];
  const float* c3 = (const float*)d_in[3];
  const float* c4 = (const float*)d_in[4];
  const float* b0 = (const float*)d_in[5];
  const float* b1 = (const float*)d_in[6];
  const float* b2 = (const float*)d_in[7];
  const float* b3 = (const float*)d_in[8];
  const float* b4 = (const float*)d_in[9];
  const float* f0 = (const float*)d_in[10];
  const float* f1 = (const float*)d_in[11];
  const float* f2 = (const float*)d_in[12];
  const float* f3 = (const float*)d_in[13];
  const float* f4 = (const float*)d_in[14];
  const float* proto = (const float*)d_in[15];
  float* out = (float*)d_out;

  float* w = (float*)d_ws;
  // workspace layout (float units):
  // bbox: [0, 1638912)  = 64*6402*4
  // thr:  [1638912, 2048768) = 64*6404 (padded stride for f4-aligned reads)
  // val:  [2458368, 3482368) = 64*16000
  // anc:  [3482368, 4506368) = 64*16000 (int)
  // csel: [4506368, 4711168) = 64*100*32
  float4* bbox = (float4*)w;
  float* thr = w + 1638912;
  float* val = w + 2458368;
  int* anc = (int*)(w + 3482368);
  float* csel = w + 4506368;

  k_prep<<<1601, 256, 0, stream>>>(c0, c1, c2, c3, c4, b0, b1, b2, b3, b4, thr, bbox);
  k_compact<<<64 * NCLS, 256, 0, stream>>>(c0, c1, c2, c3, c4, thr, val, anc);
  k_fastnms<<<64 * NCLS, 256, 0, stream>>>(bbox, val, anc);
  k_top<<<64, 256, 0, stream>>>(val, anc, bbox, f0, f1, f2, f3, f4, out, csel);
  k_mask<<<64 * 50, 256, 0, stream>>>(proto, csel, out + 38400);
}

// Round 5
// 697.258 us; speedup vs baseline: 1.1541x; 1.0168x over previous
//
#include <hip/hip_runtime.h>
#include <math.h>

typedef unsigned int u32;
typedef unsigned long long u64;

#define NANCH 6402
#define THRS 6404   // padded per-batch stride for thr (keeps float4 reads 16B-aligned)
#define NCLS 80
#define TOPK 200
#define MAXN 100

// ---------- helpers ----------
__device__ __forceinline__ u32 sortable_u32(float f) {
  u32 u = __float_as_uint(f);
  return u ^ ((u32)(((int)u) >> 31) | 0x80000000u);
}
__device__ __forceinline__ float unsortable_f(u32 u) {
  u32 f = (u & 0x80000000u) ? (u ^ 0x80000000u) : ~u;
  return __uint_as_float(f);
}

__device__ __forceinline__ u64 shfl_xor_u64(u64 v, int m) {
  u32 lo = (u32)__shfl_xor((int)(u32)(v & 0xFFFFFFFFULL), m, 64);
  u32 hi = (u32)__shfl_xor((int)(u32)(v >> 32), m, 64);
  return ((u64)hi << 32) | lo;
}

// descending bitonic sort of P (power of 2) u64 keys in LDS, 256 threads
// (fallback path for cnt>256; also used by k_top)
__device__ void bitonic_desc(u64* keys, int P, int tid) {
  for (int k = 2; k <= P; k <<= 1) {
    for (int j = k >> 1; j > 0; j >>= 1) {
      for (int i = tid; i < P; i += 256) {
        int l = i ^ j;
        if (l > i) {
          u64 a = keys[i], b = keys[l];
          bool desc = ((i & k) == 0);
          if (desc ? (a < b) : (a > b)) { keys[i] = b; keys[l] = a; }
        }
      }
      __syncthreads();
    }
  }
}

// ---------- kernel 1: softmax threshold precompute + bbox decode ----------
// thr = m + log(0.05 * den)  =>  (score > 0.05) <=> (logit > thr),
// and score = 0.05 * exp(logit - thr) (monotone, ~1e-7 rel of exp(l-m)/den).
template<int W, int HW, int BS, int OFF>
__device__ void prep_level(int t, const float* __restrict__ cls,
                           const float* __restrict__ box,
                           float* __restrict__ thr, float4* __restrict__ bbox) {
  if (t >= 64 * 3 * HW) return;
  int b = t / (3 * HW);
  int rem = t - b * 3 * HW;
  int a = rem / HW;
  int hw = rem - a * HW;

  const float* cbase = cls + ((size_t)b * 243 + (size_t)a * 81) * HW + hw;
  float m = cbase[0];
#pragma unroll 4
  for (int c = 1; c < 81; ++c) m = fmaxf(m, cbase[(size_t)c * HW]);
  double den = 0.0;
#pragma unroll 4
  for (int c = 0; c < 81; ++c) den += (double)expf(cbase[(size_t)c * HW] - m);
  // plane-major layout: p = OFF + a*HW + hw  (coalesced re-read in k_cnms)
  thr[(size_t)b * THRS + OFF + a * HW + hw] = m + logf(0.05f * (float)den);

  // bbox decode
  const float* bb = box + ((size_t)b * 12 + (size_t)a * 4) * HW + hw;
  float d0 = bb[0] * 0.1f;
  float d1 = bb[HW] * 0.1f;
  float d2 = bb[2 * HW] * 0.2f;
  float d3 = bb[3 * HW] * 0.2f;
  const float MR = 4.135166556742356f;  // |log(0.016)| cast to f32
  d2 = fminf(fmaxf(d2, -MR), MR);
  d3 = fminf(fmaxf(d3, -MR), MR);

  int x = hw % W, y = hw / W;
  double r = (a == 0) ? 0.5 : ((a == 1) ? 1.0 : 2.0);
  double hr = sqrt(r), wr = 1.0 / hr;
  double wsd = ((double)BS * wr) * 3.0;
  double hsd = ((double)BS * hr) * 3.0;
  double cc = (double)BS * 0.5;
  double sx = (double)(x * BS), sy = (double)(y * BS);
  float ax0 = (float)((cc - 0.5 * wsd) + sx);
  float ay0 = (float)((cc - 0.5 * hsd) + sy);
  float ax1 = (float)((cc + 0.5 * wsd) + sx);
  float ay1 = (float)((cc + 0.5 * hsd) + sy);

  float px = (ax0 + ax1) * 0.5f, py = (ay0 + ay1) * 0.5f;
  float pw = ax1 - ax0, ph = ay1 - ay0;
  float gx = px + pw * d0, gy = py + ph * d1;
  float gw = pw * expf(d2), gh = ph * expf(d3);
  float x0 = fminf(fmaxf(gx - 0.5f * gw, 0.f), 320.f);
  float y0 = fminf(fmaxf(gy - 0.5f * gh, 0.f), 320.f);
  float x1 = fminf(fmaxf(gx + 0.5f * gw, 0.f), 320.f);
  float y1 = fminf(fmaxf(gy + 0.5f * gh, 0.f), 320.f);
  int n = OFF + hw * 3 + a;  // anchor-major index (matches reference flatten)
  bbox[(size_t)b * NANCH + n] = make_float4(x0, y0, x1, y1);
}

__global__ __launch_bounds__(256) void k_prep(
    const float* c0, const float* c1, const float* c2, const float* c3, const float* c4,
    const float* b0, const float* b1, const float* b2, const float* b3, const float* b4,
    float* thr, float4* bbox) {
  int bid = blockIdx.x, tid = threadIdx.x;
  if (bid < 1200)      prep_level<40, 1600, 8, 0>(bid * 256 + tid, c0, b0, thr, bbox);
  else if (bid < 1500) prep_level<20, 400, 16, 4800>((bid - 1200) * 256 + tid, c1, b1, thr, bbox);
  else if (bid < 1575) prep_level<10, 100, 32, 6000>((bid - 1500) * 256 + tid, c2, b2, thr, bbox);
  else if (bid < 1594) prep_level<5, 25, 64, 6300>((bid - 1575) * 256 + tid, c3, b3, thr, bbox);
  else                 prep_level<3, 9, 128, 6375>((bid - 1594) * 256 + tid, c4, b4, thr, bbox);
}

// ---------- kernel 2: per-(batch,class) compact + top-200 sort + Fast NMS ----------
// vectorized scan (HW divisible by 4): float4 logit + float4 thr per lane
template<int HW, int OFF>
__device__ void compact_level_v(int b, int ccls, const float* __restrict__ cls,
                                const float* __restrict__ thr,
                                u64* keys, int* cnt, int tid) {
  const int NF4 = 3 * HW / 4;
  for (int idx = tid; idx < NF4; idx += 256) {
    int a = idx / (HW / 4);
    int h4 = idx - a * (HW / 4);
    float4 lv = ((const float4*)(cls + ((size_t)b * 243 + (size_t)a * 81 + ccls) * HW))[h4];
    float4 tv = ((const float4*)(thr + (size_t)b * THRS + OFF + a * HW))[h4];
    int hwb = h4 * 4;
#define CAND(le, te, ei)                                            \
    if ((le) > (te)) {                                              \
      float s = 0.05f * expf((le) - (te));                          \
      int pos = atomicAdd(cnt, 1);                                  \
      if (pos < 1024) {                                             \
        u32 n = (u32)(OFF + (hwb + (ei)) * 3 + a);                  \
        keys[pos] = ((u64)__float_as_uint(s) << 32) | (u32)(~n);    \
      }                                                             \
    }
    CAND(lv.x, tv.x, 0)
    CAND(lv.y, tv.y, 1)
    CAND(lv.z, tv.z, 2)
    CAND(lv.w, tv.w, 3)
#undef CAND
  }
}

// scalar scan for the tiny levels (HW = 25, 9)
template<int HW, int OFF>
__device__ void compact_level_s(int b, int ccls, const float* __restrict__ cls,
                                const float* __restrict__ thr,
                                u64* keys, int* cnt, int tid) {
  for (int a = 0; a < 3; ++a) {
    const float* src = cls + ((size_t)b * 243 + (size_t)a * 81 + ccls) * HW;
    const float* tp = thr + (size_t)b * THRS + OFF + a * HW;
    for (int hw = tid; hw < HW; hw += 256) {
      float l = src[hw];
      float t = tp[hw];
      if (l > t) {
        float s = 0.05f * expf(l - t);
        int pos = atomicAdd(cnt, 1);
        if (pos < 1024) {
          u32 n = (u32)(OFF + hw * 3 + a);
          keys[pos] = ((u64)__float_as_uint(s) << 32) | (u32)(~n);
        }
      }
    }
  }
}

// straight-line IoU step: guard-band cheap test (3*ov vs ai+aj), rare exact IEEE path.
// Decision is bit-identical to reference ov/max(ai+aj-ov,1e-6) > 0.5.
#define IOU_STEP(bj, aj, jcol, supvar)                                      \
  {                                                                          \
    float4 bi = boxes[i];                                                    \
    float ai = area[i];                                                      \
    float wx = fmaxf(fminf(bi.z, (bj).z) - fmaxf(bi.x, (bj).x), 0.f);        \
    float wy = fmaxf(fminf(bi.w, (bj).w) - fmaxf(bi.y, (bj).y), 0.f);        \
    float ov = wx * wy;                                                      \
    float rhs = ai + (aj);                                                   \
    float un0 = rhs - ov;                                                    \
    float t3 = 3.f * ov;                                                     \
    bool big = (un0 > 1e-5f);                                                \
    bool sure = big && (t3 > rhs * 1.02f);                                   \
    bool needx = (!big) || ((t3 > rhs * 0.98f) && !sure);                    \
    bool sp = sure;                                                          \
    if (needx) { float un = fmaxf(un0, 1e-6f); sp = (ov / un > 0.5f); }      \
    supvar = supvar || (sp && (i < (jcol)));                                 \
  }

__global__ __launch_bounds__(256) void k_cnms(
    const float* c0, const float* c1, const float* c2, const float* c3, const float* c4,
    const float* __restrict__ thr, const float4* __restrict__ bbox,
    float* __restrict__ val, int* __restrict__ anc) {
  __shared__ u64 keys[1024];
  __shared__ float4 boxes[TOPK];
  __shared__ float area[TOPK];
  __shared__ u32 suppw[8];
  __shared__ int cnt;
  int tid = threadIdx.x;
  int bid = blockIdx.x;
  int b = bid / NCLS;
  int ccls = bid - b * NCLS;
  if (tid == 0) cnt = 0;
  __syncthreads();

  compact_level_v<1600, 0>(b, ccls, c0, thr, keys, &cnt, tid);
  compact_level_v<400, 4800>(b, ccls, c1, thr, keys, &cnt, tid);
  compact_level_v<100, 6000>(b, ccls, c2, thr, keys, &cnt, tid);
  compact_level_s<25, 6300>(b, ccls, c3, thr, keys, &cnt, tid);
  compact_level_s<9, 6375>(b, ccls, c4, thr, keys, &cnt, tid);
  __syncthreads();

  int cntc = min(cnt, 1024);
  int K2 = min(cntc, TOPK);

  if (cntc <= 256) {
    // fast path (~90% of blocks): in-register bitonic-256, one key/thread.
    // 33 intra-wave stages via shfl_xor (no barriers), 3 cross-wave via LDS.
    u64 key = (tid < cntc) ? keys[tid] : 0ULL;
    for (int k = 2; k <= 256; k <<= 1) {
      for (int j = k >> 1; j > 0; j >>= 1) {
        bool lower = ((tid & j) == 0);
        bool desc = ((tid & k) == 0);
        u64 o;
        if (j >= 64) {
          keys[tid] = key;
          __syncthreads();
          o = keys[tid ^ j];
          __syncthreads();
        } else {
          o = shfl_xor_u64(key, j);
        }
        bool take_max = (lower == desc);
        key = (take_max ? (key >= o) : (key <= o)) ? key : o;
      }
    }
    keys[tid] = key;  // materialize sorted order (own slot; barrier below)
  } else {
    // rare fallback: LDS bitonic on 512/1024
    int P = (cntc <= 512) ? 512 : 1024;
    for (int i = cntc + tid; i < P; i += 256) keys[i] = 0ULL;
    __syncthreads();
    bitonic_desc(keys, P, tid);
  }
  if (tid < 8) suppw[tid] = 0u;
  __syncthreads();

  // gather boxes for the sorted top-K2
  if (tid < K2) {
    u32 n = ~(u32)(keys[tid] & 0xFFFFFFFFULL);
    float4 bx = bbox[(size_t)b * NANCH + n];
    boxes[tid] = bx;
    area[tid] = (bx.z - bx.x) * (bx.w - bx.y);
  }
  __syncthreads();

  // balanced pair-parallel Fast-NMS, straight-line (no break, wave-uniform bound):
  //   supp[j] = OR_{i<j} (iou(i,j) > 0.5)   (order-free)
  // thread t: columns {pn, K2-1-pn}, i-range parity-split by half.
  {
    int pn = tid & 127;
    int half = tid >> 7;
    int j0 = pn;
    int j1 = K2 - 1 - pn;
    bool v0 = (j0 >= 1) && (j0 < K2);
    bool v1 = (j1 >= 1) && (j1 < K2) && (j1 != j0);
    float4 bj0 = v0 ? boxes[j0] : make_float4(0.f, 0.f, 0.f, 0.f);
    float aj0 = v0 ? area[j0] : 0.f;
    float4 bj1 = v1 ? boxes[j1] : make_float4(0.f, 0.f, 0.f, 0.f);
    float aj1 = v1 ? area[j1] : 0.f;
    int m0 = v0 ? j0 : 0;
    int m1 = v1 ? j1 : 0;
#pragma unroll
    for (int s = 1; s < 64; s <<= 1) {
      m0 = max(m0, __shfl_xor(m0, s));
      m1 = max(m1, __shfl_xor(m1, s));
    }
    bool sup0 = false, sup1 = false;
#pragma unroll 2
    for (int i = half; i < m0; i += 2) IOU_STEP(bj0, aj0, j0, sup0)
#pragma unroll 2
    for (int i = half; i < m1; i += 2) IOU_STEP(bj1, aj1, j1, sup1)
    if (v0 && sup0) atomicOr(&suppw[j0 >> 5], 1u << (j0 & 31));
    if (v1 && sup1) atomicOr(&suppw[j1 >> 5], 1u << (j1 & 31));
  }
  __syncthreads();

  float* valp = val + (size_t)b * (NCLS * TOPK) + (size_t)ccls * TOPK;
  int* ancp = anc + (size_t)b * (NCLS * TOPK) + (size_t)ccls * TOPK;
  if (tid < TOPK) {
    if (tid < K2) {
      bool supp = (suppw[tid >> 5] >> (tid & 31)) & 1u;
      u64 kk = keys[tid];
      valp[tid] = supp ? -1.0f : __uint_as_float((u32)(kk >> 32));
      ancp[tid] = (int)(~(u32)kk);
    } else {
      valp[tid] = -1.0f;
      ancp[tid] = -1;
    }
  }
}

// ---------- kernel 3: per-batch global top-100 + dets/labels/coeff gather ----------
__global__ __launch_bounds__(256) void k_top(
    const float* __restrict__ val, const int* __restrict__ anc,
    const float4* __restrict__ bbox,
    const float* f0, const float* f1, const float* f2, const float* f3, const float* f4,
    float* __restrict__ out, float* __restrict__ csel) {
  int b = blockIdx.x, tid = threadIdx.x;
  const float* vp = val + (size_t)b * 16000;

  u32 uloc[63];
#pragma unroll
  for (int k = 0; k < 63; ++k) {
    int i = tid + k * 256;
    uloc[k] = (i < 16000) ? sortable_u32(vp[i]) : 0u;
  }

  __shared__ int partial[256];
  u32 lo = 0u, hi = 0xFFFFFFFFu;
  for (int it = 0; it < 32; ++it) {
    u32 mid = lo + ((hi - lo) >> 1);
    int cme = 0;
#pragma unroll
    for (int k = 0; k < 63; ++k) cme += (uloc[k] >= mid) ? 1 : 0;
    partial[tid] = cme;
    __syncthreads();
    for (int s = 128; s > 0; s >>= 1) {
      if (tid < s) partial[tid] += partial[tid + s];
      __syncthreads();
    }
    int total = partial[0];
    __syncthreads();
    if (total >= MAXN) lo = mid; else hi = mid;
  }
  u32 V = lo;  // value of the 100th largest (sortable bits)

  __shared__ u64 ckey[512];
  __shared__ int cnt2;
  if (tid == 0) cnt2 = 0;
  __syncthreads();
#pragma unroll
  for (int k = 0; k < 63; ++k) {
    int i = tid + k * 256;
    if (i < 16000 && uloc[k] >= V) {
      int p = atomicAdd(&cnt2, 1);
      if (p < 512) ckey[p] = ((u64)uloc[k] << 32) | (u32)(~(u32)i);
    }
  }
  __syncthreads();
  int m2 = min(cnt2, 512);
  for (int i = m2 + tid; i < 512; i += 256) ckey[i] = 0ULL;
  __syncthreads();
  bitonic_desc(ckey, 512, tid);

  __shared__ int selanc[MAXN];
  if (tid < MAXN) {
    u64 kk = ckey[tid];
    u32 u = (u32)(kk >> 32);
    float v = unsortable_f(u);
    u32 flat = ~(u32)(kk & 0xFFFFFFFFULL);
    int ccls = (int)(flat / 200u);
    int an = anc[(size_t)b * 16000 + flat];
    float4 bx = (an >= 0) ? bbox[(size_t)b * NANCH + an] : make_float4(0.f, 0.f, 0.f, 0.f);
    float* dout = out + (size_t)b * 500 + (size_t)tid * 5;
    dout[0] = bx.x; dout[1] = bx.y; dout[2] = bx.z; dout[3] = bx.w; dout[4] = v;
    out[32000 + (size_t)b * 100 + tid] = (float)ccls;  // labels as f32
    selanc[tid] = an;
  }
  __syncthreads();

  float* cp = csel + (size_t)b * 3200;
  for (int idx = tid; idx < 3200; idx += 256) {
    int kk = idx >> 5, q = idx & 31;
    int an = selanc[kk];
    float cv = 0.f;
    if (an >= 0) {
      if (an < 4800)      { int rel = an;        int hw = rel / 3, a = rel % 3; cv = f0[((size_t)b * 96 + (size_t)(a * 32 + q)) * 1600 + hw]; }
      else if (an < 6000) { int rel = an - 4800; int hw = rel / 3, a = rel % 3; cv = f1[((size_t)b * 96 + (size_t)(a * 32 + q)) * 400 + hw]; }
      else if (an < 6300) { int rel = an - 6000; int hw = rel / 3, a = rel % 3; cv = f2[((size_t)b * 96 + (size_t)(a * 32 + q)) * 100 + hw]; }
      else if (an < 6375) { int rel = an - 6300; int hw = rel / 3, a = rel % 3; cv = f3[((size_t)b * 96 + (size_t)(a * 32 + q)) * 25 + hw]; }
      else                { int rel = an - 6375; int hw = rel / 3, a = rel % 3; cv = f4[((size_t)b * 96 + (size_t)(a * 32 + q)) * 9 + hw]; }
    }
    cp[idx] = cv;
  }
}

// ---------- kernel 4: masks = sigmoid(proto @ cselT) ----------
// LDS-staged output -> fully coalesced float4 global stores (fixes the
// 2.5x HBM write amplification). proto rows go global->reg directly.
#define STG 116   // staging row stride (floats): 116*4B % 16 == 0 -> f4-aligned
__global__ __launch_bounds__(256) void k_mask(const float* __restrict__ proto,
                                              const float* __restrict__ csel,
                                              float* __restrict__ outm) {
  __shared__ __align__(16) float S[100 * 36];     // csel, padded stride 36
  __shared__ __align__(16) float stage[64 * STG]; // 29696 B half-tile staging
  int bid = blockIdx.x;
  int b = bid / 50, tile = bid - b * 50;
  int tid = threadIdx.x;

  const float* cs = csel + (size_t)b * 3200;
  for (int i = tid; i < 3200; i += 256) {
    int n = i >> 5, j = i & 31;
    S[n * 36 + j] = cs[i];
  }

  int q = tid & 3, r = tid >> 2;  // r in [0,64): rows r and r+64; q picks 25-col chunk
  const float* pp = proto + (size_t)b * 204800 + (size_t)tile * 4096;
  float p0[32], p1[32];
  const float4* pr0 = (const float4*)(pp + (size_t)r * 32);
  const float4* pr1 = (const float4*)(pp + (size_t)(r + 64) * 32);
#pragma unroll
  for (int jc = 0; jc < 8; ++jc) {
    float4 v0 = pr0[jc];
    p0[jc * 4 + 0] = v0.x; p0[jc * 4 + 1] = v0.y; p0[jc * 4 + 2] = v0.z; p0[jc * 4 + 3] = v0.w;
    float4 v1 = pr1[jc];
    p1[jc * 4 + 0] = v1.x; p1[jc * 4 + 1] = v1.y; p1[jc * 4 + 2] = v1.z; p1[jc * 4 + 3] = v1.w;
  }
  __syncthreads();  // S ready

  float* ob = outm + (size_t)b * 640000 + (size_t)tile * 12800;

  // ---- phase A: rows 0..63 ----
  for (int i = 0; i < 25; ++i) {
    int n = q * 25 + i;
    const float4* sp = (const float4*)&S[n * 36];
    float a0 = 0.f;
#pragma unroll
    for (int jc = 0; jc < 8; ++jc) {
      float4 sv = sp[jc];
      a0 += p0[jc * 4 + 0] * sv.x;
      a0 += p0[jc * 4 + 1] * sv.y;
      a0 += p0[jc * 4 + 2] * sv.z;
      a0 += p0[jc * 4 + 3] * sv.w;
    }
    stage[r * STG + n] = 1.f / (1.f + expf(-a0));
  }
  __syncthreads();
  // coalesced copy: 64 rows * 100 floats = 1600 float4, lane-linear addresses
  for (int f4i = tid; f4i < 1600; f4i += 256) {
    int f = f4i * 4;
    int row = f / 100, col = f - row * 100;   // 100 % 4 == 0 -> chunk stays in-row
    float4 v = *(const float4*)&stage[row * STG + col];
    ((float4*)ob)[f4i] = v;
  }
  __syncthreads();  // stage reuse

  // ---- phase B: rows 64..127 ----
  for (int i = 0; i < 25; ++i) {
    int n = q * 25 + i;
    const float4* sp = (const float4*)&S[n * 36];
    float a1 = 0.f;
#pragma unroll
    for (int jc = 0; jc < 8; ++jc) {
      float4 sv = sp[jc];
      a1 += p1[jc * 4 + 0] * sv.x;
      a1 += p1[jc * 4 + 1] * sv.y;
      a1 += p1[jc * 4 + 2] * sv.z;
      a1 += p1[jc * 4 + 3] * sv.w;
    }
    stage[r * STG + n] = 1.f / (1.f + expf(-a1));
  }
  __syncthreads();
  float* ob1 = ob + 6400;
  for (int f4i = tid; f4i < 1600; f4i += 256) {
    int f = f4i * 4;
    int row = f / 100, col = f - row * 100;
    float4 v = *(const float4*)&stage[row * STG + col];
    ((float4*)ob1)[f4i] = v;
  }
}

// ---------- launch ----------
extern "C" void kernel_launch(void* const* d_in, const int* in_sizes, int n_in,
                              void* d_out, int out_size, void* d_ws, size_t ws_size,
                              hipStream_t stream) {
  const float* c0 = (const float*)d_in[0];
  const float* c1 = (const float*)d_in[1];
  const float* c2 = (const float*)d_in[2];
  const float* c3 = (const float*)d_in[3];
  const float* c4 = (const float*)d_in[4];
  const float* b0 = (const float*)d_in[5];
  const float* b1 = (const float*)d_in[6];
  const float* b2 = (const float*)d_in[7];
  const float* b3 = (const float*)d_in[8];
  const float* b4 = (const float*)d_in[9];
  const float* f0 = (const float*)d_in[10];
  const float* f1 = (const float*)d_in[11];
  const float* f2 = (const float*)d_in[12];
  const float* f3 = (const float*)d_in[13];
  const float* f4 = (const float*)d_in[14];
  const float* proto = (const float*)d_in[15];
  float* out = (float*)d_out;

  float* w = (float*)d_ws;
  // workspace layout (float units):
  // bbox: [0, 1638912)  = 64*6402*4
  // thr:  [1638912, 2048768) = 64*6404 (padded stride for f4-aligned reads)
  // val:  [2458368, 3482368) = 64*16000
  // anc:  [3482368, 4506368) = 64*16000 (int)
  // csel: [4506368, 4711168) = 64*100*32
  float4* bbox = (float4*)w;
  float* thr = w + 1638912;
  float* val = w + 2458368;
  int* anc = (int*)(w + 3482368);
  float* csel = w + 4506368;

  k_prep<<<1601, 256, 0, stream>>>(c0, c1, c2, c3, c4, b0, b1, b2, b3, b4, thr, bbox);
  k_cnms<<<64 * NCLS, 256, 0, stream>>>(c0, c1, c2, c3, c4, thr, bbox, val, anc);
  k_top<<<64, 256, 0, stream>>>(val, anc, bbox, f0, f1, f2, f3, f4, out, csel);
  k_mask<<<64 * 50, 256, 0, stream>>>(proto, csel, out + 38400);
}